// Round 9
// baseline (553.813 us; speedup 1.0000x reference)
//
#include <hip/hip_runtime.h>
#include <hip/hip_bf16.h>

#define HH 512
#define WW 512
#define HWSZ (HH*WW)
#define NB 32
#define NLD 100000
#define NF 16
#define EPSV 1e-3f
#define TILE 16
#define GR (TILE+4)    // grid halo tile 20x20
#define YR (TILE+2)    // y1/proj tile 18x18
#define YRYR (YR*YR)   // 324
#define NGRP 21        // ceil(324/16) pixel-groups for MFMA
#define PSLOTS (NGRP*16)  // 336
#define PSTRB 10       // proj row stride in shorts (taps 0..8 + pad)

#define RGB 14              // log2 cells per scatter region
#define RCELLS (1<<RGB)     // 16384 cells = 64KB LDS
#define NREG (HWSZ/RCELLS)  // 16 regions per batch
#define CAP 8192            // region bucket capacity (λ=6250, σ=77)
#define NTILE 1024          // 32x32 tiles of 16x16
#define CAPT 256            // tile bucket capacity (λ=97.7, σ=9.9)

typedef __attribute__((ext_vector_type(8))) short bf16x8;
typedef __attribute__((ext_vector_type(4))) float f32x4;
typedef __attribute__((ext_vector_type(2))) float f32x2;

static __device__ __forceinline__ unsigned short f2bfu(float f) {
  __hip_bfloat16 h = __float2bfloat16(f);
  return __builtin_bit_cast(unsigned short, h);
}

// HW packed bf16 convert: lo16=cvt(a), hi16=cvt(b)
static __device__ __forceinline__ unsigned cvtpk(float a, float b) {
  unsigned r;
  asm("v_cvt_pk_bf16_f32 %0, %1, %2" : "=v"(r) : "v"(a), "v"(b));
  return r;
}

// packed fp32 FMA helpers (2 px per inst; weight broadcast via op_sel)
static __device__ __forceinline__ f32x2 pk_fma_lo(f32x2 w, f32x2 g, f32x2 acc) {
  asm("v_pk_fma_f32 %0, %1, %2, %0 op_sel_hi:[0,1,1]" : "+v"(acc) : "v"(w), "v"(g));
  return acc;
}
static __device__ __forceinline__ f32x2 pk_fma_hi(f32x2 w, f32x2 g, f32x2 acc) {
  asm("v_pk_fma_f32 %0, %1, %2, %0 op_sel:[1,0,0] op_sel_hi:[1,1,1]" : "+v"(acc) : "v"(w), "v"(g));
  return acc;
}
static __device__ __forceinline__ f32x2 pk_bn_lo(f32x2 a, f32x2 y, f32x2 b) {
  f32x2 d;
  asm("v_pk_fma_f32 %0, %1, %2, %3 op_sel_hi:[0,1,0]" : "=v"(d) : "v"(a), "v"(y), "v"(b));
  return d;
}
static __device__ __forceinline__ f32x2 pk_bn_hi(f32x2 a, f32x2 y, f32x2 b) {
  f32x2 d;
  asm("v_pk_fma_f32 %0, %1, %2, %3 op_sel:[1,0,1] op_sel_hi:[1,1,1]" : "=v"(d) : "v"(a), "v"(y), "v"(b));
  return d;
}

// ---- prep: build the w2 MFMA A-fragment once ----
__global__ void prep_k(const float* __restrict__ w2g, uint4* __restrict__ w2A) {
  int l = threadIdx.x;  // 64
  bf16x8 a2;
  #pragma unroll
  for (int jj = 0; jj < 8; ++jj) {
    int m = l & 15, c = (l >> 4)*8 + jj;
    float v = (m < 9 && c < NF) ? w2g[m*NF + c] : 0.f;
    a2[jj] = (short)f2bfu(v);
  }
  w2A[l] = __builtin_bit_cast(uint4, a2);
}

// ---- bin: fills region buckets (LDS-scatter) + tile buckets (fused gather) ----
__global__ __launch_bounds__(256) void bin_k(const int* __restrict__ idx,
    unsigned* __restrict__ g_cnt, unsigned* __restrict__ g_bkt,
    unsigned* __restrict__ g_tcnt, unsigned* __restrict__ g_tbkt) {
  __shared__ unsigned hr[NREG], br[NREG], ht[NTILE], bt[NTILE];
  const int lid = threadIdx.x;
  if (lid < NREG) hr[lid] = 0;
  for (int q = lid; q < NTILE; q += 256) ht[q] = 0;
  __syncthreads();
  for (int i = blockIdx.x*256 + lid; i < NLD; i += 64*256) {
    int cell = idx[i];
    atomicAdd(&hr[cell >> RGB], 1u);
    int h = cell >> 9, w = cell & 511;
    atomicAdd(&ht[(h >> 4)*32 + (w >> 4)], 1u);
  }
  __syncthreads();
  if (lid < NREG) { br[lid] = atomicAdd(&g_cnt[lid], hr[lid]); hr[lid] = 0; }
  for (int q = lid; q < NTILE; q += 256) {
    bt[q] = ht[q] ? atomicAdd(&g_tcnt[q], ht[q]) : 0u;
    ht[q] = 0;
  }
  __syncthreads();
  for (int i = blockIdx.x*256 + lid; i < NLD; i += 64*256) {
    int cell = idx[i];
    int r = cell >> RGB;
    unsigned pr = br[r] + atomicAdd(&hr[r], 1u);
    if (pr < CAP) g_bkt[(size_t)r*CAP + pr] = ((unsigned)i << RGB) | (unsigned)(cell & (RCELLS-1));
    int h = cell >> 9, w = cell & 511;
    int t = (h >> 4)*32 + (w >> 4);
    unsigned pt = bt[t] + atomicAdd(&ht[t], 1u);
    if (pt < CAPT) g_tbkt[(size_t)t*CAPT + pt] =
        ((unsigned)i << 8) | ((unsigned)(h & 15) << 4) | (unsigned)(w & 15);
  }
}

// ---- scatter via LDS-privatized regions (proven R5) ----
__global__ __launch_bounds__(256) void scatter_k(const float* __restrict__ x,
    const unsigned* __restrict__ g_cnt, const unsigned* __restrict__ g_bucket,
    float* __restrict__ grid) {
  __shared__ float s_acc[RCELLS];
  const int lid = threadIdx.x;
  const int j = blockIdx.x;
  const int b = j & 31;
  const int r = j >> 5;

  float4 z = make_float4(0.f, 0.f, 0.f, 0.f);
  for (int q = lid; q < RCELLS/4; q += 256) ((float4*)s_acc)[q] = z;
  __syncthreads();

  const unsigned n = min(g_cnt[r], (unsigned)CAP);
  const float* xb = x + (size_t)b*NLD;
  const unsigned* bk = g_bucket + (size_t)r*CAP;
  #pragma unroll 4
  for (unsigned k = lid; k < n; k += 256) {
    unsigned e = bk[k];
    atomicAdd(&s_acc[e & (RCELLS-1)], xb[e >> RGB]);   // ds_add_f32
  }
  __syncthreads();

  float* gout = grid + (size_t)b*HWSZ + ((size_t)r << RGB);
  for (int q = lid; q < RCELLS/4; q += 256)
    ((float4*)gout)[q] = ((const float4*)s_acc)[q];
}

__global__ __launch_bounds__(256, 8) void conv_k(const float* __restrict__ grid,
    const float* __restrict__ w1g, const float* __restrict__ b1g,
    const float* __restrict__ gammag, const float* __restrict__ betag,
    const float* __restrict__ mmg, const float* __restrict__ mvg,
    const uint4* __restrict__ w2Ag, const float* __restrict__ b2g,
    const float* __restrict__ x,
    const unsigned* __restrict__ g_tcnt, const unsigned* __restrict__ g_tbkt,
    float* __restrict__ out)
{
  __shared__ float s_grid[GR*GR];                       // reused as y-tile in epilogue
  __shared__ __align__(16) short s_y1b[PSLOTS][NF];     // y1 post-BN, bf16 (10.75 KB)
  __shared__ __align__(8) unsigned short s_projb[PSLOTS*PSTRB];  // proj bf16 (6.7 KB)
  __shared__ __align__(16) float s_w1[9][NF];
  __shared__ __align__(16) float s_b1[NF], s_bnA[NF], s_bnB[NF];
  // total ~19.9 KB -> 8 blocks/CU

  const int lid = threadIdx.x;
  const int j = blockIdx.x;
  const int b = j & 31;                    // XCD-affine batch
  const int tile = j >> 5;
  const int ty0 = (tile >> 5) * TILE, tx0 = (tile & 31) * TILE;
  const float* gb = grid + (size_t)b*HWSZ;

  const int l = lid & 63;
  const int wid = lid >> 6;
  const bf16x8 w2frag = __builtin_bit_cast(bf16x8, w2Ag[l]);

  if (lid < 144) s_w1[lid/NF][lid%NF] = w1g[lid];
  if (lid >= 192 && lid < 192+NF) {
    int c = lid - 192;
    float sc = gammag[c] * rsqrtf(mvg[c] + EPSV);
    s_bnA[c] = sc;
    s_bnB[c] = betag[c] - mmg[c]*sc;
    s_b1[c] = b1g[c];
  }

  // stage grid halo tile, NON-TEMPORAL (don't evict out/x lines from L2)
  for (int q = lid; q < GR*GR; q += 256) {
    int r = q / GR, c = q - r*GR;
    int gh = ty0 - 2 + r, gw = tx0 - 2 + c;
    float v = 0.f;
    if ((unsigned)gh < HH && (unsigned)gw < WW)
      v = __builtin_nontemporal_load(gb + gh*WW + gw);
    s_grid[q] = v;
  }
  __syncthreads();

  // ---- fused A+P: each wave owns a 32-px window (2 MFMA groups) per iter;
  // y1 write -> lgkmcnt(0) -> own-wave MFMA. No cross-wave barrier needed. ----
  {
    const int k = l & 3, pr = l >> 2, c0 = k*4;   // A roles: quad k, pair pr
    const int n_px = l & 15, kg = l >> 4;         // P roles
    f32x2 rwp[9][2];
    #pragma unroll
    for (int t = 0; t < 9; ++t) {
      float4 w4 = *(const float4*)&s_w1[t][c0];
      rwp[t][0] = (f32x2){w4.x, w4.y};
      rwp[t][1] = (f32x2){w4.z, w4.w};
    }
    float4 a4 = *(const float4*)&s_bnA[c0];
    float4 b4 = *(const float4*)&s_bnB[c0];
    float4 i4 = *(const float4*)&s_b1[c0];
    f32x2 rap[2] = {(f32x2){a4.x, a4.y}, (f32x2){a4.z, a4.w}};
    f32x2 rbp[2] = {(f32x2){b4.x, b4.y}, (f32x2){b4.z, b4.w}};

    #pragma unroll
    for (int gi = 0; gi < 3; ++gi) {
      const int G0 = 2*wid + 8*gi;          // first group of this wave's window
      if (G0 < NGRP) {
        // ---- A-part: pixel-pair (p0, p0+1), 4 channels ----
        int p0 = G0*16 + pr*2;              // even; pair never straddles a row (YR=18 even)
        if (p0 < PSLOTS) {
          unsigned rr = ((unsigned)p0 * 3641u) >> 16;   // p0/18
          unsigned cc = (unsigned)p0 - rr*18u;
          int yh = ty0 - 1 + (int)rr;
          int yw0 = tx0 - 1 + (int)cc;
          bool v0 = ((unsigned)yh < HH) & ((unsigned)yw0 < WW);
          bool v1 = ((unsigned)yh < HH) & ((unsigned)(yw0+1) < WW);
          const float* gp = &s_grid[rr*GR + cc];
          f32x2 ac0 = (f32x2){i4.x, i4.x}, ac1 = (f32x2){i4.y, i4.y};
          f32x2 ac2 = (f32x2){i4.z, i4.z}, ac3 = (f32x2){i4.w, i4.w};
          #pragma unroll
          for (int dy = 0; dy < 3; ++dy)
            #pragma unroll
            for (int dx = 0; dx < 3; ++dx) {
              f32x2 g2;
              g2.x = gp[dy*GR + dx];
              g2.y = gp[dy*GR + dx + 1];
              int t = dy*3 + dx;
              ac0 = pk_fma_lo(rwp[t][0], g2, ac0);
              ac1 = pk_fma_hi(rwp[t][0], g2, ac1);
              ac2 = pk_fma_lo(rwp[t][1], g2, ac2);
              ac3 = pk_fma_hi(rwp[t][1], g2, ac3);
            }
          ac0.x = fmaxf(ac0.x, 0.f); ac0.y = fmaxf(ac0.y, 0.f);
          ac1.x = fmaxf(ac1.x, 0.f); ac1.y = fmaxf(ac1.y, 0.f);
          ac2.x = fmaxf(ac2.x, 0.f); ac2.y = fmaxf(ac2.y, 0.f);
          ac3.x = fmaxf(ac3.x, 0.f); ac3.y = fmaxf(ac3.y, 0.f);
          ac0 = pk_bn_lo(rap[0], ac0, rbp[0]);
          ac1 = pk_bn_hi(rap[0], ac1, rbp[0]);
          ac2 = pk_bn_lo(rap[1], ac2, rbp[1]);
          ac3 = pk_bn_hi(rap[1], ac3, rbp[1]);
          unsigned u00 = cvtpk(ac0.x, ac1.x), u01 = cvtpk(ac2.x, ac3.x);
          unsigned u10 = cvtpk(ac0.y, ac1.y), u11 = cvtpk(ac2.y, ac3.y);
          u00 = v0 ? u00 : 0u;  u01 = v0 ? u01 : 0u;  // OOB y1 -> 0
          u10 = v1 ? u10 : 0u;  u11 = v1 ? u11 : 0u;
          *(uint2*)&s_y1b[p0][c0]     = make_uint2(u00, u01);
          *(uint2*)&s_y1b[p0 + 1][c0] = make_uint2(u10, u11);
        }
        // wave's own LDS writes complete before its own reads below
        asm volatile("s_waitcnt lgkmcnt(0)" ::: "memory");
        __builtin_amdgcn_sched_barrier(0);
        // ---- P-part: one MFMA per 16-px group ----
        #pragma unroll
        for (int h2 = 0; h2 < 2; ++h2) {
          int g2 = G0 + h2;
          if (g2 < NGRP) {
            int p = g2*16 + n_px;
            bf16x8 bfrag = {0,0,0,0,0,0,0,0};
            if (l < 32) bfrag = *(const bf16x8*)&s_y1b[p][kg*8];
            f32x4 d = {0.f,0.f,0.f,0.f};
            d = __builtin_amdgcn_mfma_f32_16x16x32_bf16(w2frag, bfrag, d, 0, 0, 0);
            // C: col=px(lane&15), row=tap((lane>>4)*4+reg)
            if (kg < 2) {
              unsigned q0 = cvtpk(d[0], d[1]), q1 = cvtpk(d[2], d[3]);
              *(uint2*)&s_projb[p*PSTRB + kg*4] = make_uint2(q0, q1);
            } else if (kg == 2) {
              s_projb[p*PSTRB + 8] = (unsigned short)(cvtpk(d[0], d[0]) & 0xFFFFu);  // tap 8
            }
          }
        }
      }
    }
  }
  __syncthreads();

  // ---- phase B: out-tile = b2 + sum_t proj[t] at shifted pixel -> LDS ----
  {
    const int ty = lid >> 4, tx = lid & 15;
    float acc = b2g[0];
    #pragma unroll
    for (int kh = 0; kh < 3; ++kh)
      #pragma unroll
      for (int kw = 0; kw < 3; ++kw) {
        unsigned u = s_projb[((ty+kh)*YR + tx+kw)*PSTRB + kh*3+kw];
        acc += __uint_as_float(u << 16);
      }
    s_grid[lid] = acc;    // s_grid reused as the 16x16 y-tile
  }
  __syncthreads();

  // ---- fused gather epilogue ----
  {
    const unsigned nT = min(g_tcnt[tile], (unsigned)CAPT);
    const unsigned* tb = g_tbkt + (size_t)tile*CAPT;
    for (unsigned k2 = lid; k2 < nT; k2 += 256) {
      unsigned e = tb[k2];
      unsigned i = e >> 8;
      unsigned py = (e >> 4) & 15, px = e & 15;
      out[(size_t)b*NLD + i] = x[(size_t)b*NLD + i] + s_grid[py*16 + px];
    }
  }
}

extern "C" void kernel_launch(void* const* d_in, const int* in_sizes, int n_in,
                              void* d_out, int out_size, void* d_ws, size_t ws_size,
                              hipStream_t stream) {
  const float* x     = (const float*)d_in[0];
  const float* w1    = (const float*)d_in[1];
  const float* b1    = (const float*)d_in[2];
  const float* gamma = (const float*)d_in[3];
  const float* beta  = (const float*)d_in[4];
  const float* mmean = (const float*)d_in[5];
  const float* mvar  = (const float*)d_in[6];
  const float* w2    = (const float*)d_in[7];
  const float* b2    = (const float*)d_in[8];
  const int*   idx   = (const int*)d_in[9];
  float* out = (float*)d_out;

  float*    grid   = (float*)d_ws;                        // 33.55 MB
  unsigned* g_cnt  = (unsigned*)(grid + (size_t)NB*HWSZ); // 16
  unsigned* g_tcnt = g_cnt + NREG;                        // 1024
  unsigned* g_bkt  = g_tcnt + NTILE;                      // 512 KB
  unsigned* g_tbkt = g_bkt + (size_t)NREG*CAP;            // 1 MB
  uint4*    w2A    = (uint4*)(g_tbkt + (size_t)NTILE*CAPT);

  (void)hipMemsetAsync(g_cnt, 0, (NREG + NTILE)*sizeof(unsigned), stream);

  prep_k<<<dim3(1), dim3(64), 0, stream>>>(w2, w2A);

  bin_k<<<dim3(64), dim3(256), 0, stream>>>(idx, g_cnt, g_bkt, g_tcnt, g_tbkt);

  scatter_k<<<dim3(NB*NREG), dim3(256), 0, stream>>>(x, g_cnt, g_bkt, grid);

  conv_k<<<dim3(32 * (HH/TILE) * (WW/TILE)), dim3(256), 0, stream>>>(
      grid, w1, b1, gamma, beta, mmean, mvar, w2A, b2, x, g_tcnt, g_tbkt, out);
}

// Round 10
// 476.735 us; speedup vs baseline: 1.1617x; 1.1617x over previous
//
#include <hip/hip_runtime.h>
#include <hip/hip_bf16.h>

#define HH 512
#define WW 512
#define HWSZ (HH*WW)
#define NB 32
#define NLD 100000
#define NF 16
#define EPSV 1e-3f
#define TILE 16
#define GR (TILE+4)    // grid halo tile 20x20
#define YR (TILE+2)    // y1/proj tile 18x18
#define YRYR (YR*YR)   // 324
#define NGRP 21        // ceil(324/16) pixel-groups for MFMA
#define PSLOTS (NGRP*16)  // 336
#define PSTRB 10       // proj row stride in shorts (taps 0..8 + pad)

#define RGB 14              // log2 cells per scatter region
#define RCELLS (1<<RGB)     // 16384 cells = 64KB LDS
#define NREG (HWSZ/RCELLS)  // 16 regions per batch
#define CAP 8192            // region bucket capacity (λ=6250, σ=77)
#define NTILE 1024          // 32x32 tiles of 16x16
#define CAPT 256            // tile bucket capacity (λ=97.7, σ=9.9)

typedef __attribute__((ext_vector_type(8))) short bf16x8;
typedef __attribute__((ext_vector_type(4))) float f32x4;
typedef __attribute__((ext_vector_type(2))) float f32x2;

static __device__ __forceinline__ unsigned short f2bfu(float f) {
  __hip_bfloat16 h = __float2bfloat16(f);
  return __builtin_bit_cast(unsigned short, h);
}

// HW packed bf16 convert: lo16=cvt(a), hi16=cvt(b)
static __device__ __forceinline__ unsigned cvtpk(float a, float b) {
  unsigned r;
  asm("v_cvt_pk_bf16_f32 %0, %1, %2" : "=v"(r) : "v"(a), "v"(b));
  return r;
}

// packed fp32 FMA helpers (2 px per inst; weight broadcast via op_sel)
static __device__ __forceinline__ f32x2 pk_fma_lo(f32x2 w, f32x2 g, f32x2 acc) {
  asm("v_pk_fma_f32 %0, %1, %2, %0 op_sel_hi:[0,1,1]" : "+v"(acc) : "v"(w), "v"(g));
  return acc;
}
static __device__ __forceinline__ f32x2 pk_fma_hi(f32x2 w, f32x2 g, f32x2 acc) {
  asm("v_pk_fma_f32 %0, %1, %2, %0 op_sel:[1,0,0] op_sel_hi:[1,1,1]" : "+v"(acc) : "v"(w), "v"(g));
  return acc;
}
static __device__ __forceinline__ f32x2 pk_bn_lo(f32x2 a, f32x2 y, f32x2 b) {
  f32x2 d;
  asm("v_pk_fma_f32 %0, %1, %2, %3 op_sel_hi:[0,1,0]" : "=v"(d) : "v"(a), "v"(y), "v"(b));
  return d;
}
static __device__ __forceinline__ f32x2 pk_bn_hi(f32x2 a, f32x2 y, f32x2 b) {
  f32x2 d;
  asm("v_pk_fma_f32 %0, %1, %2, %3 op_sel:[1,0,1] op_sel_hi:[1,1,1]" : "=v"(d) : "v"(a), "v"(y), "v"(b));
  return d;
}

// ---- prep: build the w2 MFMA A-fragment once ----
__global__ void prep_k(const float* __restrict__ w2g, uint4* __restrict__ w2A) {
  int l = threadIdx.x;  // 64
  bf16x8 a2;
  #pragma unroll
  for (int jj = 0; jj < 8; ++jj) {
    int m = l & 15, c = (l >> 4)*8 + jj;
    float v = (m < 9 && c < NF) ? w2g[m*NF + c] : 0.f;
    a2[jj] = (short)f2bfu(v);
  }
  w2A[l] = __builtin_bit_cast(uint4, a2);
}

// ---- bin: fills region buckets (LDS-scatter) + tile buckets (fused gather) ----
__global__ __launch_bounds__(256) void bin_k(const int* __restrict__ idx,
    unsigned* __restrict__ g_cnt, unsigned* __restrict__ g_bkt,
    unsigned* __restrict__ g_tcnt, unsigned* __restrict__ g_tbkt) {
  __shared__ unsigned hr[NREG], br[NREG], ht[NTILE], bt[NTILE];
  const int lid = threadIdx.x;
  if (lid < NREG) hr[lid] = 0;
  for (int q = lid; q < NTILE; q += 256) ht[q] = 0;
  __syncthreads();
  for (int i = blockIdx.x*256 + lid; i < NLD; i += 64*256) {
    int cell = idx[i];
    atomicAdd(&hr[cell >> RGB], 1u);
    int h = cell >> 9, w = cell & 511;
    atomicAdd(&ht[(h >> 4)*32 + (w >> 4)], 1u);
  }
  __syncthreads();
  if (lid < NREG) { br[lid] = atomicAdd(&g_cnt[lid], hr[lid]); hr[lid] = 0; }
  for (int q = lid; q < NTILE; q += 256) {
    bt[q] = ht[q] ? atomicAdd(&g_tcnt[q], ht[q]) : 0u;
    ht[q] = 0;
  }
  __syncthreads();
  for (int i = blockIdx.x*256 + lid; i < NLD; i += 64*256) {
    int cell = idx[i];
    int r = cell >> RGB;
    unsigned pr = br[r] + atomicAdd(&hr[r], 1u);
    if (pr < CAP) g_bkt[(size_t)r*CAP + pr] = ((unsigned)i << RGB) | (unsigned)(cell & (RCELLS-1));
    int h = cell >> 9, w = cell & 511;
    int t = (h >> 4)*32 + (w >> 4);
    unsigned pt = bt[t] + atomicAdd(&ht[t], 1u);
    if (pt < CAPT) g_tbkt[(size_t)t*CAPT + pt] =
        ((unsigned)i << 8) | ((unsigned)(h & 15) << 4) | (unsigned)(w & 15);
  }
}

// ---- scatter via LDS-privatized regions (proven R5) ----
__global__ __launch_bounds__(256) void scatter_k(const float* __restrict__ x,
    const unsigned* __restrict__ g_cnt, const unsigned* __restrict__ g_bucket,
    float* __restrict__ grid) {
  __shared__ float s_acc[RCELLS];
  const int lid = threadIdx.x;
  const int j = blockIdx.x;
  const int b = j & 31;
  const int r = j >> 5;

  float4 z = make_float4(0.f, 0.f, 0.f, 0.f);
  for (int q = lid; q < RCELLS/4; q += 256) ((float4*)s_acc)[q] = z;
  __syncthreads();

  const unsigned n = min(g_cnt[r], (unsigned)CAP);
  const float* xb = x + (size_t)b*NLD;
  const unsigned* bk = g_bucket + (size_t)r*CAP;
  #pragma unroll 4
  for (unsigned k = lid; k < n; k += 256) {
    unsigned e = bk[k];
    atomicAdd(&s_acc[e & (RCELLS-1)], xb[e >> RGB]);   // ds_add_f32
  }
  __syncthreads();

  float* gout = grid + (size_t)b*HWSZ + ((size_t)r << RGB);
  for (int q = lid; q < RCELLS/4; q += 256)
    ((float4*)gout)[q] = ((const float4*)s_acc)[q];
}

__global__ __launch_bounds__(256, 8) void conv_k(const float* __restrict__ grid,
    const float* __restrict__ w1g, const float* __restrict__ b1g,
    const float* __restrict__ gammag, const float* __restrict__ betag,
    const float* __restrict__ mmg, const float* __restrict__ mvg,
    const uint4* __restrict__ w2Ag, const float* __restrict__ b2g,
    const float* __restrict__ x,
    const unsigned* __restrict__ g_tcnt, const unsigned* __restrict__ g_tbkt,
    float* __restrict__ out)
{
  __shared__ float s_grid[GR*GR];                       // reused as y-tile in epilogue
  __shared__ __align__(16) short s_y1b[PSLOTS][NF];     // y1 post-BN, bf16 (10.75 KB)
  __shared__ __align__(8) unsigned short s_projb[PSLOTS*PSTRB];  // proj bf16 (6.7 KB)
  __shared__ __align__(16) float s_w1[9][NF];
  __shared__ __align__(16) float s_b1[NF], s_bnA[NF], s_bnB[NF];
  // total ~19.9 KB -> 8 blocks/CU

  const int lid = threadIdx.x;
  const int j = blockIdx.x;
  const int b = j & 31;                    // XCD-affine batch
  const int tile = j >> 5;
  const int ty0 = (tile >> 5) * TILE, tx0 = (tile & 31) * TILE;
  const float* gb = grid + (size_t)b*HWSZ;

  const int l = lid & 63;
  const int wid = lid >> 6;
  const bf16x8 w2frag = __builtin_bit_cast(bf16x8, w2Ag[l]);

  if (lid < 144) s_w1[lid/NF][lid%NF] = w1g[lid];
  if (lid >= 192 && lid < 192+NF) {
    int c = lid - 192;
    float sc = gammag[c] * rsqrtf(mvg[c] + EPSV);
    s_bnA[c] = sc;
    s_bnB[c] = betag[c] - mmg[c]*sc;
    s_b1[c] = b1g[c];
  }

  // stage grid halo tile (plain cached loads — NT loads were a 26x overfetch, R9)
  for (int q = lid; q < GR*GR; q += 256) {
    int r = q / GR, c = q - r*GR;
    int gh = ty0 - 2 + r, gw = tx0 - 2 + c;
    float v = 0.f;
    if ((unsigned)gh < HH && (unsigned)gw < WW) v = gb[gh*WW + gw];
    s_grid[q] = v;
  }
  __syncthreads();

  // ---- fused A+P: each wave owns a 32-px window (2 MFMA groups) per iter;
  // y1 write -> lgkmcnt(0) -> own-wave MFMA. No cross-wave barrier needed. ----
  {
    const int k = l & 3, pr = l >> 2, c0 = k*4;   // A roles: quad k, pair pr
    const int n_px = l & 15, kg = l >> 4;         // P roles
    f32x2 rwp[9][2];
    #pragma unroll
    for (int t = 0; t < 9; ++t) {
      float4 w4 = *(const float4*)&s_w1[t][c0];
      rwp[t][0] = (f32x2){w4.x, w4.y};
      rwp[t][1] = (f32x2){w4.z, w4.w};
    }
    float4 a4 = *(const float4*)&s_bnA[c0];
    float4 b4 = *(const float4*)&s_bnB[c0];
    float4 i4 = *(const float4*)&s_b1[c0];
    f32x2 rap[2] = {(f32x2){a4.x, a4.y}, (f32x2){a4.z, a4.w}};
    f32x2 rbp[2] = {(f32x2){b4.x, b4.y}, (f32x2){b4.z, b4.w}};

    #pragma unroll
    for (int gi = 0; gi < 3; ++gi) {
      const int G0 = 2*wid + 8*gi;          // first group of this wave's window
      if (G0 < NGRP) {
        // ---- A-part: pixel-pair (p0, p0+1), 4 channels ----
        int p0 = G0*16 + pr*2;              // even; pair never straddles a row (YR=18 even)
        if (p0 < PSLOTS) {
          unsigned rr = ((unsigned)p0 * 3641u) >> 16;   // p0/18
          unsigned cc = (unsigned)p0 - rr*18u;
          int yh = ty0 - 1 + (int)rr;
          int yw0 = tx0 - 1 + (int)cc;
          bool v0 = ((unsigned)yh < HH) & ((unsigned)yw0 < WW);
          bool v1 = ((unsigned)yh < HH) & ((unsigned)(yw0+1) < WW);
          const float* gp = &s_grid[rr*GR + cc];
          f32x2 ac0 = (f32x2){i4.x, i4.x}, ac1 = (f32x2){i4.y, i4.y};
          f32x2 ac2 = (f32x2){i4.z, i4.z}, ac3 = (f32x2){i4.w, i4.w};
          #pragma unroll
          for (int dy = 0; dy < 3; ++dy)
            #pragma unroll
            for (int dx = 0; dx < 3; ++dx) {
              f32x2 g2;
              g2.x = gp[dy*GR + dx];
              g2.y = gp[dy*GR + dx + 1];
              int t = dy*3 + dx;
              ac0 = pk_fma_lo(rwp[t][0], g2, ac0);
              ac1 = pk_fma_hi(rwp[t][0], g2, ac1);
              ac2 = pk_fma_lo(rwp[t][1], g2, ac2);
              ac3 = pk_fma_hi(rwp[t][1], g2, ac3);
            }
          ac0.x = fmaxf(ac0.x, 0.f); ac0.y = fmaxf(ac0.y, 0.f);
          ac1.x = fmaxf(ac1.x, 0.f); ac1.y = fmaxf(ac1.y, 0.f);
          ac2.x = fmaxf(ac2.x, 0.f); ac2.y = fmaxf(ac2.y, 0.f);
          ac3.x = fmaxf(ac3.x, 0.f); ac3.y = fmaxf(ac3.y, 0.f);
          ac0 = pk_bn_lo(rap[0], ac0, rbp[0]);
          ac1 = pk_bn_hi(rap[0], ac1, rbp[0]);
          ac2 = pk_bn_lo(rap[1], ac2, rbp[1]);
          ac3 = pk_bn_hi(rap[1], ac3, rbp[1]);
          unsigned u00 = cvtpk(ac0.x, ac1.x), u01 = cvtpk(ac2.x, ac3.x);
          unsigned u10 = cvtpk(ac0.y, ac1.y), u11 = cvtpk(ac2.y, ac3.y);
          u00 = v0 ? u00 : 0u;  u01 = v0 ? u01 : 0u;  // OOB y1 -> 0
          u10 = v1 ? u10 : 0u;  u11 = v1 ? u11 : 0u;
          *(uint2*)&s_y1b[p0][c0]     = make_uint2(u00, u01);
          *(uint2*)&s_y1b[p0 + 1][c0] = make_uint2(u10, u11);
        }
        // wave's own LDS writes complete before its own reads below
        asm volatile("s_waitcnt lgkmcnt(0)" ::: "memory");
        __builtin_amdgcn_sched_barrier(0);
        // ---- P-part: one MFMA per 16-px group ----
        #pragma unroll
        for (int h2 = 0; h2 < 2; ++h2) {
          int g2 = G0 + h2;
          if (g2 < NGRP) {
            int p = g2*16 + n_px;
            bf16x8 bfrag = {0,0,0,0,0,0,0,0};
            if (l < 32) bfrag = *(const bf16x8*)&s_y1b[p][kg*8];
            f32x4 d = {0.f,0.f,0.f,0.f};
            d = __builtin_amdgcn_mfma_f32_16x16x32_bf16(w2frag, bfrag, d, 0, 0, 0);
            // C: col=px(lane&15), row=tap((lane>>4)*4+reg)
            if (kg < 2) {
              unsigned q0 = cvtpk(d[0], d[1]), q1 = cvtpk(d[2], d[3]);
              *(uint2*)&s_projb[p*PSTRB + kg*4] = make_uint2(q0, q1);
            } else if (kg == 2) {
              s_projb[p*PSTRB + 8] = (unsigned short)(cvtpk(d[0], d[0]) & 0xFFFFu);  // tap 8
            }
          }
        }
      }
    }
  }
  __syncthreads();

  // ---- phase B: out-tile = b2 + sum_t proj[t] at shifted pixel -> LDS ----
  {
    const int ty = lid >> 4, tx = lid & 15;
    float acc = b2g[0];
    #pragma unroll
    for (int kh = 0; kh < 3; ++kh)
      #pragma unroll
      for (int kw = 0; kw < 3; ++kw) {
        unsigned u = s_projb[((ty+kh)*YR + tx+kw)*PSTRB + kh*3+kw];
        acc += __uint_as_float(u << 16);
      }
    s_grid[lid] = acc;    // s_grid reused as the 16x16 y-tile
  }
  __syncthreads();

  // ---- fused gather epilogue ----
  {
    const unsigned nT = min(g_tcnt[tile], (unsigned)CAPT);
    const unsigned* tb = g_tbkt + (size_t)tile*CAPT;
    for (unsigned k2 = lid; k2 < nT; k2 += 256) {
      unsigned e = tb[k2];
      unsigned i = e >> 8;
      unsigned py = (e >> 4) & 15, px = e & 15;
      out[(size_t)b*NLD + i] = x[(size_t)b*NLD + i] + s_grid[py*16 + px];
    }
  }
}

extern "C" void kernel_launch(void* const* d_in, const int* in_sizes, int n_in,
                              void* d_out, int out_size, void* d_ws, size_t ws_size,
                              hipStream_t stream) {
  const float* x     = (const float*)d_in[0];
  const float* w1    = (const float*)d_in[1];
  const float* b1    = (const float*)d_in[2];
  const float* gamma = (const float*)d_in[3];
  const float* beta  = (const float*)d_in[4];
  const float* mmean = (const float*)d_in[5];
  const float* mvar  = (const float*)d_in[6];
  const float* w2    = (const float*)d_in[7];
  const float* b2    = (const float*)d_in[8];
  const int*   idx   = (const int*)d_in[9];
  float* out = (float*)d_out;

  float*    grid   = (float*)d_ws;                        // 33.55 MB
  unsigned* g_cnt  = (unsigned*)(grid + (size_t)NB*HWSZ); // 16
  unsigned* g_tcnt = g_cnt + NREG;                        // 1024
  unsigned* g_bkt  = g_tcnt + NTILE;                      // 512 KB
  unsigned* g_tbkt = g_bkt + (size_t)NREG*CAP;            // 1 MB
  uint4*    w2A    = (uint4*)(g_tbkt + (size_t)NTILE*CAPT);

  (void)hipMemsetAsync(g_cnt, 0, (NREG + NTILE)*sizeof(unsigned), stream);

  prep_k<<<dim3(1), dim3(64), 0, stream>>>(w2, w2A);

  bin_k<<<dim3(64), dim3(256), 0, stream>>>(idx, g_cnt, g_bkt, g_tcnt, g_tbkt);

  scatter_k<<<dim3(NB*NREG), dim3(256), 0, stream>>>(x, g_cnt, g_bkt, grid);

  conv_k<<<dim3(32 * (HH/TILE) * (WW/TILE)), dim3(256), 0, stream>>>(
      grid, w1, b1, gamma, beta, mmean, mvar, w2A, b2, x, g_tcnt, g_tbkt, out);
}

// Round 11
// 161.343 us; speedup vs baseline: 3.4325x; 2.9548x over previous
//
#include <hip/hip_runtime.h>
#include <hip/hip_bf16.h>

#define HH 512
#define WW 512
#define HWSZ (HH*WW)
#define NB 32
#define NLD 100000
#define NF 16
#define EPSV 1e-3f
#define TILE 16
#define GR (TILE+4)    // grid halo tile 20x20
#define YR (TILE+2)    // y1/proj tile 18x18
#define YRYR (YR*YR)   // 324
#define NGRP 21        // ceil(324/16) pixel-groups for MFMA
#define PSLOTS (NGRP*16)  // 336
#define PSTRB 10       // proj row stride in shorts (taps 0..8 + pad)

#define RGB 14              // log2 cells per scatter region
#define RCELLS (1<<RGB)     // 16384 cells = 64KB LDS
#define NREG (HWSZ/RCELLS)  // 16 regions per batch
#define CAP 8192            // region bucket capacity (λ=6250, σ=77)
#define NTILE 1024          // 32x32 tiles of 16x16
#define CAPT 256            // tile bucket capacity (λ=97.7, σ=9.9)

typedef __attribute__((ext_vector_type(8))) short bf16x8;
typedef __attribute__((ext_vector_type(4))) float f32x4;
typedef __attribute__((ext_vector_type(2))) float f32x2;

static __device__ __forceinline__ unsigned short f2bfu(float f) {
  __hip_bfloat16 h = __float2bfloat16(f);
  return __builtin_bit_cast(unsigned short, h);
}

// HW packed bf16 convert: lo16=cvt(a), hi16=cvt(b)
static __device__ __forceinline__ unsigned cvtpk(float a, float b) {
  unsigned r;
  asm("v_cvt_pk_bf16_f32 %0, %1, %2" : "=v"(r) : "v"(a), "v"(b));
  return r;
}

// packed fp32 FMA helpers (2 px per inst; weight broadcast via op_sel)
static __device__ __forceinline__ f32x2 pk_fma_lo(f32x2 w, f32x2 g, f32x2 acc) {
  asm("v_pk_fma_f32 %0, %1, %2, %0 op_sel_hi:[0,1,1]" : "+v"(acc) : "v"(w), "v"(g));
  return acc;
}
static __device__ __forceinline__ f32x2 pk_fma_hi(f32x2 w, f32x2 g, f32x2 acc) {
  asm("v_pk_fma_f32 %0, %1, %2, %0 op_sel:[1,0,0] op_sel_hi:[1,1,1]" : "+v"(acc) : "v"(w), "v"(g));
  return acc;
}
static __device__ __forceinline__ f32x2 pk_bn_lo(f32x2 a, f32x2 y, f32x2 b) {
  f32x2 d;
  asm("v_pk_fma_f32 %0, %1, %2, %3 op_sel_hi:[0,1,0]" : "=v"(d) : "v"(a), "v"(y), "v"(b));
  return d;
}
static __device__ __forceinline__ f32x2 pk_bn_hi(f32x2 a, f32x2 y, f32x2 b) {
  f32x2 d;
  asm("v_pk_fma_f32 %0, %1, %2, %3 op_sel:[1,0,1] op_sel_hi:[1,1,1]" : "=v"(d) : "v"(a), "v"(y), "v"(b));
  return d;
}

// ---- prep: build the w2 MFMA A-fragment once ----
__global__ void prep_k(const float* __restrict__ w2g, uint4* __restrict__ w2A) {
  int l = threadIdx.x;  // 64
  bf16x8 a2;
  #pragma unroll
  for (int jj = 0; jj < 8; ++jj) {
    int m = l & 15, c = (l >> 4)*8 + jj;
    float v = (m < 9 && c < NF) ? w2g[m*NF + c] : 0.f;
    a2[jj] = (short)f2bfu(v);
  }
  w2A[l] = __builtin_bit_cast(uint4, a2);
}

// ---- bin: fills region buckets (LDS-scatter) + tile buckets (fused gather) ----
__global__ __launch_bounds__(256) void bin_k(const int* __restrict__ idx,
    unsigned* __restrict__ g_cnt, unsigned* __restrict__ g_bkt,
    unsigned* __restrict__ g_tcnt, unsigned* __restrict__ g_tbkt) {
  __shared__ unsigned hr[NREG], br[NREG], ht[NTILE], bt[NTILE];
  const int lid = threadIdx.x;
  if (lid < NREG) hr[lid] = 0;
  for (int q = lid; q < NTILE; q += 256) ht[q] = 0;
  __syncthreads();
  for (int i = blockIdx.x*256 + lid; i < NLD; i += 64*256) {
    int cell = idx[i];
    atomicAdd(&hr[cell >> RGB], 1u);
    int h = cell >> 9, w = cell & 511;
    atomicAdd(&ht[(h >> 4)*32 + (w >> 4)], 1u);
  }
  __syncthreads();
  if (lid < NREG) { br[lid] = atomicAdd(&g_cnt[lid], hr[lid]); hr[lid] = 0; }
  for (int q = lid; q < NTILE; q += 256) {
    bt[q] = ht[q] ? atomicAdd(&g_tcnt[q], ht[q]) : 0u;
    ht[q] = 0;
  }
  __syncthreads();
  for (int i = blockIdx.x*256 + lid; i < NLD; i += 64*256) {
    int cell = idx[i];
    int r = cell >> RGB;
    unsigned pr = br[r] + atomicAdd(&hr[r], 1u);
    if (pr < CAP) g_bkt[(size_t)r*CAP + pr] = ((unsigned)i << RGB) | (unsigned)(cell & (RCELLS-1));
    int h = cell >> 9, w = cell & 511;
    int t = (h >> 4)*32 + (w >> 4);
    unsigned pt = bt[t] + atomicAdd(&ht[t], 1u);
    if (pt < CAPT) g_tbkt[(size_t)t*CAPT + pt] =
        ((unsigned)i << 8) | ((unsigned)(h & 15) << 4) | (unsigned)(w & 15);
  }
}

// ---- scatter via LDS-privatized regions (proven R5) ----
__global__ __launch_bounds__(256) void scatter_k(const float* __restrict__ x,
    const unsigned* __restrict__ g_cnt, const unsigned* __restrict__ g_bucket,
    float* __restrict__ grid) {
  __shared__ float s_acc[RCELLS];
  const int lid = threadIdx.x;
  const int j = blockIdx.x;
  const int b = j & 31;
  const int r = j >> 5;

  float4 z = make_float4(0.f, 0.f, 0.f, 0.f);
  for (int q = lid; q < RCELLS/4; q += 256) ((float4*)s_acc)[q] = z;
  __syncthreads();

  const unsigned n = min(g_cnt[r], (unsigned)CAP);
  const float* xb = x + (size_t)b*NLD;
  const unsigned* bk = g_bucket + (size_t)r*CAP;
  #pragma unroll 4
  for (unsigned k = lid; k < n; k += 256) {
    unsigned e = bk[k];
    atomicAdd(&s_acc[e & (RCELLS-1)], xb[e >> RGB]);   // ds_add_f32
  }
  __syncthreads();

  float* gout = grid + (size_t)b*HWSZ + ((size_t)r << RGB);
  for (int q = lid; q < RCELLS/4; q += 256)
    ((float4*)gout)[q] = ((const float4*)s_acc)[q];
}

// launch_bounds (256,4): cap VGPR at 128. R9's (256,8) clamped VGPR to 32 and
// SPILLED TO SCRATCH (FETCH 26MB->938MB, WRITE 150MB->1.06GB). LDS 19.9KB still
// allows 8 blocks/CU when the compiler lands <=64 VGPR on its own.
__global__ __launch_bounds__(256, 4) void conv_k(const float* __restrict__ grid,
    const float* __restrict__ w1g, const float* __restrict__ b1g,
    const float* __restrict__ gammag, const float* __restrict__ betag,
    const float* __restrict__ mmg, const float* __restrict__ mvg,
    const uint4* __restrict__ w2Ag, const float* __restrict__ b2g,
    const float* __restrict__ x,
    const unsigned* __restrict__ g_tcnt, const unsigned* __restrict__ g_tbkt,
    float* __restrict__ out)
{
  __shared__ float s_grid[GR*GR];                       // reused as y-tile in epilogue
  __shared__ __align__(16) short s_y1b[PSLOTS][NF];     // y1 post-BN, bf16 (10.75 KB)
  __shared__ __align__(8) unsigned short s_projb[PSLOTS*PSTRB];  // proj bf16 (6.7 KB)
  __shared__ __align__(16) float s_w1[9][NF];
  __shared__ __align__(16) float s_b1[NF], s_bnA[NF], s_bnB[NF];
  // total ~19.9 KB -> 8 blocks/CU

  const int lid = threadIdx.x;
  const int j = blockIdx.x;
  const int b = j & 31;                    // XCD-affine batch
  const int tile = j >> 5;
  const int ty0 = (tile >> 5) * TILE, tx0 = (tile & 31) * TILE;
  const float* gb = grid + (size_t)b*HWSZ;

  const int l = lid & 63;
  const int wid = lid >> 6;
  const bf16x8 w2frag = __builtin_bit_cast(bf16x8, w2Ag[l]);

  if (lid < 144) s_w1[lid/NF][lid%NF] = w1g[lid];
  if (lid >= 192 && lid < 192+NF) {
    int c = lid - 192;
    float sc = gammag[c] * rsqrtf(mvg[c] + EPSV);
    s_bnA[c] = sc;
    s_bnB[c] = betag[c] - mmg[c]*sc;
    s_b1[c] = b1g[c];
  }

  // stage grid halo tile (plain cached loads)
  for (int q = lid; q < GR*GR; q += 256) {
    int r = q / GR, c = q - r*GR;
    int gh = ty0 - 2 + r, gw = tx0 - 2 + c;
    float v = 0.f;
    if ((unsigned)gh < HH && (unsigned)gw < WW) v = gb[gh*WW + gw];
    s_grid[q] = v;
  }
  __syncthreads();

  // ---- fused A+P: each wave owns a 32-px window (2 MFMA groups) per iter;
  // y1 write -> lgkmcnt(0) -> own-wave MFMA. No cross-wave barrier needed. ----
  {
    const int k = l & 3, pr = l >> 2, c0 = k*4;   // A roles: quad k, pair pr
    const int n_px = l & 15, kg = l >> 4;         // P roles
    f32x2 rwp[9][2];
    #pragma unroll
    for (int t = 0; t < 9; ++t) {
      float4 w4 = *(const float4*)&s_w1[t][c0];
      rwp[t][0] = (f32x2){w4.x, w4.y};
      rwp[t][1] = (f32x2){w4.z, w4.w};
    }
    float4 a4 = *(const float4*)&s_bnA[c0];
    float4 b4 = *(const float4*)&s_bnB[c0];
    float4 i4 = *(const float4*)&s_b1[c0];
    f32x2 rap[2] = {(f32x2){a4.x, a4.y}, (f32x2){a4.z, a4.w}};
    f32x2 rbp[2] = {(f32x2){b4.x, b4.y}, (f32x2){b4.z, b4.w}};

    #pragma unroll
    for (int gi = 0; gi < 3; ++gi) {
      const int G0 = 2*wid + 8*gi;          // first group of this wave's window
      if (G0 < NGRP) {
        // ---- A-part: pixel-pair (p0, p0+1), 4 channels ----
        int p0 = G0*16 + pr*2;              // even; pair never straddles a row (YR=18 even)
        if (p0 < PSLOTS) {
          unsigned rr = ((unsigned)p0 * 3641u) >> 16;   // p0/18
          unsigned cc = (unsigned)p0 - rr*18u;
          int yh = ty0 - 1 + (int)rr;
          int yw0 = tx0 - 1 + (int)cc;
          bool v0 = ((unsigned)yh < HH) & ((unsigned)yw0 < WW);
          bool v1 = ((unsigned)yh < HH) & ((unsigned)(yw0+1) < WW);
          const float* gp = &s_grid[rr*GR + cc];
          f32x2 ac0 = (f32x2){i4.x, i4.x}, ac1 = (f32x2){i4.y, i4.y};
          f32x2 ac2 = (f32x2){i4.z, i4.z}, ac3 = (f32x2){i4.w, i4.w};
          #pragma unroll
          for (int dy = 0; dy < 3; ++dy)
            #pragma unroll
            for (int dx = 0; dx < 3; ++dx) {
              f32x2 g2;
              g2.x = gp[dy*GR + dx];
              g2.y = gp[dy*GR + dx + 1];
              int t = dy*3 + dx;
              ac0 = pk_fma_lo(rwp[t][0], g2, ac0);
              ac1 = pk_fma_hi(rwp[t][0], g2, ac1);
              ac2 = pk_fma_lo(rwp[t][1], g2, ac2);
              ac3 = pk_fma_hi(rwp[t][1], g2, ac3);
            }
          ac0.x = fmaxf(ac0.x, 0.f); ac0.y = fmaxf(ac0.y, 0.f);
          ac1.x = fmaxf(ac1.x, 0.f); ac1.y = fmaxf(ac1.y, 0.f);
          ac2.x = fmaxf(ac2.x, 0.f); ac2.y = fmaxf(ac2.y, 0.f);
          ac3.x = fmaxf(ac3.x, 0.f); ac3.y = fmaxf(ac3.y, 0.f);
          ac0 = pk_bn_lo(rap[0], ac0, rbp[0]);
          ac1 = pk_bn_hi(rap[0], ac1, rbp[0]);
          ac2 = pk_bn_lo(rap[1], ac2, rbp[1]);
          ac3 = pk_bn_hi(rap[1], ac3, rbp[1]);
          unsigned u00 = cvtpk(ac0.x, ac1.x), u01 = cvtpk(ac2.x, ac3.x);
          unsigned u10 = cvtpk(ac0.y, ac1.y), u11 = cvtpk(ac2.y, ac3.y);
          u00 = v0 ? u00 : 0u;  u01 = v0 ? u01 : 0u;  // OOB y1 -> 0
          u10 = v1 ? u10 : 0u;  u11 = v1 ? u11 : 0u;
          *(uint2*)&s_y1b[p0][c0]     = make_uint2(u00, u01);
          *(uint2*)&s_y1b[p0 + 1][c0] = make_uint2(u10, u11);
        }
        // wave's own LDS writes complete before its own reads below
        asm volatile("s_waitcnt lgkmcnt(0)" ::: "memory");
        __builtin_amdgcn_sched_barrier(0);
        // ---- P-part: one MFMA per 16-px group ----
        #pragma unroll
        for (int h2 = 0; h2 < 2; ++h2) {
          int g2 = G0 + h2;
          if (g2 < NGRP) {
            int p = g2*16 + n_px;
            bf16x8 bfrag = {0,0,0,0,0,0,0,0};
            if (l < 32) bfrag = *(const bf16x8*)&s_y1b[p][kg*8];
            f32x4 d = {0.f,0.f,0.f,0.f};
            d = __builtin_amdgcn_mfma_f32_16x16x32_bf16(w2frag, bfrag, d, 0, 0, 0);
            // C: col=px(lane&15), row=tap((lane>>4)*4+reg)
            if (kg < 2) {
              unsigned q0 = cvtpk(d[0], d[1]), q1 = cvtpk(d[2], d[3]);
              *(uint2*)&s_projb[p*PSTRB + kg*4] = make_uint2(q0, q1);
            } else if (kg == 2) {
              s_projb[p*PSTRB + 8] = (unsigned short)(cvtpk(d[0], d[0]) & 0xFFFFu);  // tap 8
            }
          }
        }
      }
    }
  }
  __syncthreads();

  // ---- phase B: out-tile = b2 + sum_t proj[t] at shifted pixel -> LDS ----
  {
    const int ty = lid >> 4, tx = lid & 15;
    float acc = b2g[0];
    #pragma unroll
    for (int kh = 0; kh < 3; ++kh)
      #pragma unroll
      for (int kw = 0; kw < 3; ++kw) {
        unsigned u = s_projb[((ty+kh)*YR + tx+kw)*PSTRB + kh*3+kw];
        acc += __uint_as_float(u << 16);
      }
    s_grid[lid] = acc;    // s_grid reused as the 16x16 y-tile
  }
  __syncthreads();

  // ---- fused gather epilogue ----
  {
    const unsigned nT = min(g_tcnt[tile], (unsigned)CAPT);
    const unsigned* tb = g_tbkt + (size_t)tile*CAPT;
    for (unsigned k2 = lid; k2 < nT; k2 += 256) {
      unsigned e = tb[k2];
      unsigned i = e >> 8;
      unsigned py = (e >> 4) & 15, px = e & 15;
      out[(size_t)b*NLD + i] = x[(size_t)b*NLD + i] + s_grid[py*16 + px];
    }
  }
}

extern "C" void kernel_launch(void* const* d_in, const int* in_sizes, int n_in,
                              void* d_out, int out_size, void* d_ws, size_t ws_size,
                              hipStream_t stream) {
  const float* x     = (const float*)d_in[0];
  const float* w1    = (const float*)d_in[1];
  const float* b1    = (const float*)d_in[2];
  const float* gamma = (const float*)d_in[3];
  const float* beta  = (const float*)d_in[4];
  const float* mmean = (const float*)d_in[5];
  const float* mvar  = (const float*)d_in[6];
  const float* w2    = (const float*)d_in[7];
  const float* b2    = (const float*)d_in[8];
  const int*   idx   = (const int*)d_in[9];
  float* out = (float*)d_out;

  float*    grid   = (float*)d_ws;                        // 33.55 MB
  unsigned* g_cnt  = (unsigned*)(grid + (size_t)NB*HWSZ); // 16
  unsigned* g_tcnt = g_cnt + NREG;                        // 1024
  unsigned* g_bkt  = g_tcnt + NTILE;                      // 512 KB
  unsigned* g_tbkt = g_bkt + (size_t)NREG*CAP;            // 1 MB
  uint4*    w2A    = (uint4*)(g_tbkt + (size_t)NTILE*CAPT);

  (void)hipMemsetAsync(g_cnt, 0, (NREG + NTILE)*sizeof(unsigned), stream);

  prep_k<<<dim3(1), dim3(64), 0, stream>>>(w2, w2A);

  bin_k<<<dim3(64), dim3(256), 0, stream>>>(idx, g_cnt, g_bkt, g_tcnt, g_tbkt);

  scatter_k<<<dim3(NB*NREG), dim3(256), 0, stream>>>(x, g_cnt, g_bkt, grid);

  conv_k<<<dim3(32 * (HH/TILE) * (WW/TILE)), dim3(256), 0, stream>>>(
      grid, w1, b1, gamma, beta, mmean, mvar, w2A, b2, x, g_tcnt, g_tbkt, out);
}

// Round 12
// 131.386 us; speedup vs baseline: 4.2152x; 1.2280x over previous
//
#include <hip/hip_runtime.h>
#include <hip/hip_bf16.h>

#define HH 512
#define WW 512
#define HWSZ (HH*WW)
#define NB 32
#define NLD 100000
#define NF 16
#define EPSV 1e-3f
#define TILE 16
#define GR (TILE+4)    // grid halo tile 20x20
#define YR (TILE+2)    // y1/proj tile 18x18
#define YRYR (YR*YR)   // 324
#define NGRP 21        // ceil(324/16) pixel-groups for MFMA
#define PSLOTS (NGRP*16)  // 336
#define PSTRB 10       // proj row stride in shorts (taps 0..8 + pad)

#define RGB 14              // log2 cells per scatter region
#define RCELLS (1<<RGB)     // 16384 cells = 64KB LDS
#define NREG (HWSZ/RCELLS)  // 16 regions per batch
#define CAP 8192            // region bucket capacity (λ=6250, σ=77)
#define NTILE 1024          // 32x32 tiles of 16x16
#define CAPT 256            // tile bucket capacity (λ=97.7, σ=9.9)

typedef __attribute__((ext_vector_type(8))) short bf16x8;
typedef __attribute__((ext_vector_type(4))) float f32x4;

static __device__ __forceinline__ unsigned short f2bfu(float f) {
  __hip_bfloat16 h = __float2bfloat16(f);
  return __builtin_bit_cast(unsigned short, h);
}

// HW packed bf16 convert: lo16=cvt(a), hi16=cvt(b)
static __device__ __forceinline__ unsigned cvtpk(float a, float b) {
  unsigned r;
  asm("v_cvt_pk_bf16_f32 %0, %1, %2" : "=v"(r) : "v"(a), "v"(b));
  return r;
}

// ---- prep: build BOTH MFMA A-fragments once.
// w2A: A[m=tap][k=ch] (proj);  w1A: A[m=ch][k=tap] (conv1). Lane l holds
// m=l&15, k=(l>>4)*8+jj. ----
__global__ void prep_k(const float* __restrict__ w1g, const float* __restrict__ w2g,
                       uint4* __restrict__ w2A, uint4* __restrict__ w1A) {
  int l = threadIdx.x;  // 64
  bf16x8 a2, a1;
  #pragma unroll
  for (int jj = 0; jj < 8; ++jj) {
    int m = l & 15, k = (l >> 4)*8 + jj;
    float v2 = (m < 9 && k < NF) ? w2g[m*NF + k] : 0.f;   // w2[tap][ch]
    float v1 = (k < 9)           ? w1g[k*NF + m] : 0.f;   // w1[tap][ch] -> A[ch][tap]
    a2[jj] = (short)f2bfu(v2);
    a1[jj] = (short)f2bfu(v1);
  }
  w2A[l] = __builtin_bit_cast(uint4, a2);
  w1A[l] = __builtin_bit_cast(uint4, a1);
}

// ---- bin: fills region buckets (LDS-scatter) + tile buckets (fused gather) ----
__global__ __launch_bounds__(256) void bin_k(const int* __restrict__ idx,
    unsigned* __restrict__ g_cnt, unsigned* __restrict__ g_bkt,
    unsigned* __restrict__ g_tcnt, unsigned* __restrict__ g_tbkt) {
  __shared__ unsigned hr[NREG], br[NREG], ht[NTILE], bt[NTILE];
  const int lid = threadIdx.x;
  if (lid < NREG) hr[lid] = 0;
  for (int q = lid; q < NTILE; q += 256) ht[q] = 0;
  __syncthreads();
  for (int i = blockIdx.x*256 + lid; i < NLD; i += 64*256) {
    int cell = idx[i];
    atomicAdd(&hr[cell >> RGB], 1u);
    int h = cell >> 9, w = cell & 511;
    atomicAdd(&ht[(h >> 4)*32 + (w >> 4)], 1u);
  }
  __syncthreads();
  if (lid < NREG) { br[lid] = atomicAdd(&g_cnt[lid], hr[lid]); hr[lid] = 0; }
  for (int q = lid; q < NTILE; q += 256) {
    bt[q] = ht[q] ? atomicAdd(&g_tcnt[q], ht[q]) : 0u;
    ht[q] = 0;
  }
  __syncthreads();
  for (int i = blockIdx.x*256 + lid; i < NLD; i += 64*256) {
    int cell = idx[i];
    int r = cell >> RGB;
    unsigned pr = br[r] + atomicAdd(&hr[r], 1u);
    if (pr < CAP) g_bkt[(size_t)r*CAP + pr] = ((unsigned)i << RGB) | (unsigned)(cell & (RCELLS-1));
    int h = cell >> 9, w = cell & 511;
    int t = (h >> 4)*32 + (w >> 4);
    unsigned pt = bt[t] + atomicAdd(&ht[t], 1u);
    if (pt < CAPT) g_tbkt[(size_t)t*CAPT + pt] =
        ((unsigned)i << 8) | ((unsigned)(h & 15) << 4) | (unsigned)(w & 15);
  }
}

// ---- scatter via LDS-privatized regions (proven R5) ----
__global__ __launch_bounds__(256) void scatter_k(const float* __restrict__ x,
    const unsigned* __restrict__ g_cnt, const unsigned* __restrict__ g_bucket,
    float* __restrict__ grid) {
  __shared__ float s_acc[RCELLS];
  const int lid = threadIdx.x;
  const int j = blockIdx.x;
  const int b = j & 31;
  const int r = j >> 5;

  float4 z = make_float4(0.f, 0.f, 0.f, 0.f);
  for (int q = lid; q < RCELLS/4; q += 256) ((float4*)s_acc)[q] = z;
  __syncthreads();

  const unsigned n = min(g_cnt[r], (unsigned)CAP);
  const float* xb = x + (size_t)b*NLD;
  const unsigned* bk = g_bucket + (size_t)r*CAP;
  #pragma unroll 4
  for (unsigned k = lid; k < n; k += 256) {
    unsigned e = bk[k];
    atomicAdd(&s_acc[e & (RCELLS-1)], xb[e >> RGB]);   // ds_add_f32
  }
  __syncthreads();

  float* gout = grid + (size_t)b*HWSZ + ((size_t)r << RGB);
  for (int q = lid; q < RCELLS/4; q += 256)
    ((float4*)gout)[q] = ((const float4*)s_acc)[q];
}

// ---- conv: BOTH convs on the matrix pipe. Per 16-px group:
//   MFMA1 (w1A x G) -> lane: 4ch of 1px -> bias/relu/BN in regs ->
//   cvtpk -> 4x ds_bpermute regroup (4ch/lane -> 8ch/lane) -> MFMA2 (w2A x Y1)
//   -> proj taps to LDS. No y1 LDS array, no intra-phase barrier. ----
__global__ __launch_bounds__(256, 4) void conv_k(const float* __restrict__ grid,
    const float* __restrict__ b1g,
    const float* __restrict__ gammag, const float* __restrict__ betag,
    const float* __restrict__ mmg, const float* __restrict__ mvg,
    const uint4* __restrict__ w1Ag, const uint4* __restrict__ w2Ag,
    const float* __restrict__ b2g, const float* __restrict__ x,
    const unsigned* __restrict__ g_tcnt, const unsigned* __restrict__ g_tbkt,
    float* __restrict__ out)
{
  __shared__ unsigned short s_gridb[GR*GR];             // halo tile, bf16 (800 B)
  __shared__ __align__(8) unsigned short s_projb[PSLOTS*PSTRB];  // proj bf16 (6.7 KB)
  __shared__ float s_ytile[256];                        // final y tile
  __shared__ __align__(16) float s_b1[NF], s_bnA[NF], s_bnB[NF];
  // total ~9 KB LDS

  const int lid = threadIdx.x;
  const int j = blockIdx.x;
  const int b = j & 31;                    // XCD-affine batch
  const int tile = j >> 5;
  const int ty0 = (tile >> 5) * TILE, tx0 = (tile & 31) * TILE;
  const float* gb = grid + (size_t)b*HWSZ;

  const int l = lid & 63;
  const int wid = lid >> 6;
  const bf16x8 w1frag = __builtin_bit_cast(bf16x8, w1Ag[l]);
  const bf16x8 w2frag = __builtin_bit_cast(bf16x8, w2Ag[l]);

  if (lid >= 192 && lid < 192+NF) {
    int c = lid - 192;
    float sc = gammag[c] * rsqrtf(mvg[c] + EPSV);
    s_bnA[c] = sc;
    s_bnB[c] = betag[c] - mmg[c]*sc;
    s_b1[c] = b1g[c];
  }

  // stage grid halo tile as bf16 (zero = SAME padding for conv1)
  for (int q = lid; q < GR*GR; q += 256) {
    int r = q / GR, c = q - r*GR;
    int gh = ty0 - 2 + r, gw = tx0 - 2 + c;
    float v = 0.f;
    if ((unsigned)gh < HH && (unsigned)gw < WW) v = gb[gh*WW + gw];
    s_gridb[q] = (unsigned short)(cvtpk(v, v) & 0xFFFFu);
  }
  __syncthreads();

  // ---- A+P on matrix pipe ----
  {
    const int n_px = l & 15, kg = l >> 4;
    const int ce = kg * 4;                 // this lane's conv1-output channel group
    const float4 eb = *(const float4*)&s_b1[ce];
    const float4 ea = *(const float4*)&s_bnA[ce];
    const float4 eB = *(const float4*)&s_bnB[ce];
    const int srcA = (n_px + (kg & 1)*32) * 4;   // bpermute byte indices
    const int srcB = srcA + 16*4;

    for (int grp = wid; grp < NGRP; grp += 4) {
      int p = grp*16 + n_px;
      unsigned rr = ((unsigned)p * 3641u) >> 16;     // p/18
      unsigned cc = (unsigned)p - rr*18u;
      int yh = ty0 - 1 + (int)rr, yw = tx0 - 1 + (int)cc;
      bool val = ((unsigned)yh < HH) & ((unsigned)yw < WW);
      const unsigned short* gpb = &s_gridb[rr*GR + cc];

      // G-frag: B[k=tap][n=px]; kg0 holds taps 0..7, kg1 tap 8, kg2/3 zero
      uint4 gu = make_uint4(0u, 0u, 0u, 0u);
      if (kg == 0) {
        gu.x = (unsigned)gpb[0]      | ((unsigned)gpb[1]      << 16);
        gu.y = (unsigned)gpb[2]      | ((unsigned)gpb[GR]     << 16);
        gu.z = (unsigned)gpb[GR+1]   | ((unsigned)gpb[GR+2]   << 16);
        gu.w = (unsigned)gpb[2*GR]   | ((unsigned)gpb[2*GR+1] << 16);
      } else if (kg == 1) {
        gu.x = (unsigned)gpb[2*GR+2];
      }
      bf16x8 gfrag = __builtin_bit_cast(bf16x8, gu);

      // conv1: D[m=ch][n=px] -> lane holds px=n_px, ch ce..ce+3
      f32x4 d1 = {0.f, 0.f, 0.f, 0.f};
      d1 = __builtin_amdgcn_mfma_f32_16x16x32_bf16(w1frag, gfrag, d1, 0, 0, 0);

      // bias + relu + BN, then pack; OOB y1 -> 0 (conv2 pads conv1 OUTPUT)
      float y0 = fmaf(fmaxf(d1[0] + eb.x, 0.f), ea.x, eB.x);
      float y1 = fmaf(fmaxf(d1[1] + eb.y, 0.f), ea.y, eB.y);
      float y2 = fmaf(fmaxf(d1[2] + eb.z, 0.f), ea.z, eB.z);
      float y3 = fmaf(fmaxf(d1[3] + eb.w, 0.f), ea.w, eB.w);
      unsigned u0 = val ? cvtpk(y0, y1) : 0u;   // ch {ce,ce+1}
      unsigned u1 = val ? cvtpk(y2, y3) : 0u;   // ch {ce+2,ce+3}

      // regroup 4ch/lane -> 8ch/lane (proj B-frag) via wave-internal bpermute
      unsigned B0 = __builtin_amdgcn_ds_bpermute(srcA, (int)u0);
      unsigned B1 = __builtin_amdgcn_ds_bpermute(srcA, (int)u1);
      unsigned B2 = __builtin_amdgcn_ds_bpermute(srcB, (int)u0);
      unsigned B3 = __builtin_amdgcn_ds_bpermute(srcB, (int)u1);
      if (kg >= 2) { B0 = B1 = B2 = B3 = 0u; }
      bf16x8 bfrag = __builtin_bit_cast(bf16x8, make_uint4(B0, B1, B2, B3));

      // proj: D[m=tap][n=px]
      f32x4 d = {0.f, 0.f, 0.f, 0.f};
      d = __builtin_amdgcn_mfma_f32_16x16x32_bf16(w2frag, bfrag, d, 0, 0, 0);
      if (kg < 2) {
        unsigned q0 = cvtpk(d[0], d[1]), q1 = cvtpk(d[2], d[3]);
        *(uint2*)&s_projb[p*PSTRB + kg*4] = make_uint2(q0, q1);
      } else if (kg == 2) {
        s_projb[p*PSTRB + 8] = (unsigned short)(cvtpk(d[0], d[0]) & 0xFFFFu);  // tap 8
      }
    }
  }
  __syncthreads();

  // ---- phase B: out-tile = b2 + sum_t proj[t] at shifted pixel -> LDS ----
  {
    const int ty = lid >> 4, tx = lid & 15;
    float acc = b2g[0];
    #pragma unroll
    for (int kh = 0; kh < 3; ++kh)
      #pragma unroll
      for (int kw = 0; kw < 3; ++kw) {
        unsigned u = s_projb[((ty+kh)*YR + tx+kw)*PSTRB + kh*3+kw];
        acc += __uint_as_float(u << 16);
      }
    s_ytile[lid] = acc;
  }
  __syncthreads();

  // ---- fused gather epilogue ----
  {
    const unsigned nT = min(g_tcnt[tile], (unsigned)CAPT);
    const unsigned* tb = g_tbkt + (size_t)tile*CAPT;
    for (unsigned k2 = lid; k2 < nT; k2 += 256) {
      unsigned e = tb[k2];
      unsigned i = e >> 8;
      unsigned py = (e >> 4) & 15, px = e & 15;
      out[(size_t)b*NLD + i] = x[(size_t)b*NLD + i] + s_ytile[py*16 + px];
    }
  }
}

extern "C" void kernel_launch(void* const* d_in, const int* in_sizes, int n_in,
                              void* d_out, int out_size, void* d_ws, size_t ws_size,
                              hipStream_t stream) {
  const float* x     = (const float*)d_in[0];
  const float* w1    = (const float*)d_in[1];
  const float* b1    = (const float*)d_in[2];
  const float* gamma = (const float*)d_in[3];
  const float* beta  = (const float*)d_in[4];
  const float* mmean = (const float*)d_in[5];
  const float* mvar  = (const float*)d_in[6];
  const float* w2    = (const float*)d_in[7];
  const float* b2    = (const float*)d_in[8];
  const int*   idx   = (const int*)d_in[9];
  float* out = (float*)d_out;

  float*    grid   = (float*)d_ws;                        // 33.55 MB
  unsigned* g_cnt  = (unsigned*)(grid + (size_t)NB*HWSZ); // 16
  unsigned* g_tcnt = g_cnt + NREG;                        // 1024
  unsigned* g_bkt  = g_tcnt + NTILE;                      // 512 KB
  unsigned* g_tbkt = g_bkt + (size_t)NREG*CAP;            // 1 MB
  uint4*    w2A    = (uint4*)(g_tbkt + (size_t)NTILE*CAPT);
  uint4*    w1A    = w2A + 64;

  (void)hipMemsetAsync(g_cnt, 0, (NREG + NTILE)*sizeof(unsigned), stream);

  prep_k<<<dim3(1), dim3(64), 0, stream>>>(w1, w2, w2A, w1A);

  bin_k<<<dim3(64), dim3(256), 0, stream>>>(idx, g_cnt, g_bkt, g_tcnt, g_tbkt);

  scatter_k<<<dim3(NB*NREG), dim3(256), 0, stream>>>(x, g_cnt, g_bkt, grid);

  conv_k<<<dim3(32 * (HH/TILE) * (WW/TILE)), dim3(256), 0, stream>>>(
      grid, b1, gamma, beta, mmean, mvar, w1A, w2A, b2, x, g_tcnt, g_tbkt, out);
}